// Round 4
// baseline (1555.031 us; speedup 1.0000x reference)
//
#include <hip/hip_runtime.h>
#include <math.h>

// EmergentResonator — MFMA split-f16, R4.
// 256 blocks x 16 rows, 512 threads (8 waves x 3 n-tiles).
// R4 change vs R3: the step-invariant B_hi fragments (3 tiles x 12 kt x 4 VGPR
// = 144 VGPRs) are pinned in registers before the t-loop; only B_lo streams
// from L2 (halves the 576 KB/step/CU W_rec traffic that dominated R3).
// kt-loop fully unrolled so the pinned array is register-indexed.
// Occupancy is LDS-bound at 2 waves/SIMD, so VGPR budget is 256/thread — free.

#define NET    360
#define NPAD   384
#define K8N    48          // NPAD/8 k8-groups for W_rec
#define RPB    16
#define NBLK   256
#define NTHR   512         // 8 waves; wave w owns n-tiles 3w..3w+2
#define NTILE  3

typedef _Float16 f16x8 __attribute__((ext_vector_type(8)));
typedef float    f32x4 __attribute__((ext_vector_type(4)));

#define WREC_E (K8N * NPAD * 8)    // 147456 f16 per term
#define WIN_E  (4 * NPAD * 8)      // 12288 f16 per term (K pad 32)

// Split fp32 weights into f16 hi/lo in MFMA B-fragment layout:
// idx = (k8*NPAD + n)*8 + (k&7), B[k][n] = W[n*K + k], zero-padded.
__global__ void prep_kernel(const float* __restrict__ W_rec,
                            const float* __restrict__ W_in,
                            const float* __restrict__ W_gate,
                            _Float16* __restrict__ Bh, _Float16* __restrict__ Bl,
                            _Float16* __restrict__ Wio)
{
    int idx = blockIdx.x * 256 + threadIdx.x;
    if (idx < WREC_E) {
        int k8 = idx / (NPAD * 8), rem = idx % (NPAD * 8);
        int n = rem >> 3, j = rem & 7, k = k8 * 8 + j;
        float v = (k < NET && n < NET) ? W_rec[n * NET + k] : 0.f;
        _Float16 h = (_Float16)v;
        Bh[idx] = h; Bl[idx] = (_Float16)(v - (float)h);
    } else if (idx < WREC_E + 2 * WIN_E) {
        // Wio layout: [0]=Wih, [1]=Wil, [2]=Wgh, [3]=Wgl, each WIN_E f16.
        int e = idx - WREC_E;                 // 0 .. 2*WIN_E-1
        int which = e / WIN_E;                // 0 = W_in, 1 = W_gate
        int f = e % WIN_E;
        int k8 = f / (NPAD * 8), rem = f % (NPAD * 8);
        int n = rem >> 3, j = rem & 7, k = k8 * 8 + j;
        const float* W = which ? W_gate : W_in;
        float v = (k < 28 && n < NET) ? W[n * 28 + k] : 0.f;
        _Float16 h = (_Float16)v;
        Wio[(2 * which) * WIN_E + f]     = h;
        Wio[(2 * which + 1) * WIN_E + f] = (_Float16)(v - (float)h);
    }
}

__device__ __forceinline__ float sigm(float v) { return 1.f / (1.f + __expf(-v)); }

__global__ __launch_bounds__(NTHR, 2)
void resonator_kernel(const float* __restrict__ x,
                      const int*   __restrict__ rsteps_p,
                      const float* __restrict__ b_in,
                      const float* __restrict__ b_gate,
                      const float* __restrict__ ln_g,
                      const float* __restrict__ ln_b,
                      const float* __restrict__ thr_p,
                      const float* __restrict__ intr_p,
                      const float* __restrict__ steep_p,
                      const float* __restrict__ reset_p,
                      const float* __restrict__ W_cls,
                      const float* __restrict__ b_cls,
                      const _Float16* __restrict__ Bh_g,
                      const _Float16* __restrict__ Bl_g,
                      const _Float16* __restrict__ Wio_g,
                      float* __restrict__ out)
{
    // Spikes in A-fragment layout, f16 hi/lo: idx = (k8*16 + m)*8 + (k&7)
    __shared__ __align__(16) _Float16 Ah[K8N * RPB * 8];   // 12 KB
    __shared__ __align__(16) _Float16 Al[K8N * RPB * 8];   // 12 KB
    __shared__ __align__(16) _Float16 xh[4 * RPB * 8];     // 1 KB  (x_t, K pad 32)
    __shared__ __align__(16) _Float16 xl[4 * RPB * 8];     // 1 KB
    __shared__ __align__(16) _Float16 Wio[4 * WIN_E];      // 96 KB: Wih,Wil,Wgh,Wgl
    __shared__ float red[8][RPB][2];
    __shared__ float musig[2][RPB];

    const int tid  = threadIdx.x;
    const int w    = tid >> 6;
    const int lane = tid & 63;
    const int quad = lane >> 4;
    const int l15  = lane & 15;
    const int row0 = blockIdx.x * RPB;

    // Per-column params for this thread's NTILE n-values (n = (w*3+i)*16 + l15)
    float gam[NTILE], bet[NTILE], thrv[NTILE], intv[NTILE], asp[NTILE], rscv[NTILE],
          binv[NTILE], bgtv[NTILE];
#pragma unroll
    for (int i = 0; i < NTILE; ++i) {
        int n_i = (w * NTILE + i) * 16 + l15;
        bool a = n_i < NET;
        gam[i]  = a ? ln_g[n_i]   : 0.f;
        bet[i]  = a ? ln_b[n_i]   : 0.f;
        thrv[i] = a ? thr_p[n_i]  : 0.f;
        intv[i] = a ? intr_p[n_i] : 0.f;
        asp[i]  = a ? fabsf(steep_p[n_i]) : 0.f;
        rscv[i] = a ? reset_p[n_i] : 0.f;
        binv[i] = a ? b_in[n_i]   : 0.f;
        bgtv[i] = a ? b_gate[n_i] : 0.f;
    }

    float pot[NTILE][4];
#pragma unroll
    for (int i = 0; i < NTILE; ++i)
#pragma unroll
        for (int r = 0; r < 4; ++r) pot[i][r] = 0.f;

    // Zero-init spike/x LDS; stage input-weight LDS from global (uint4 copies).
    for (int e = tid; e < K8N * RPB * 8; e += NTHR) { Ah[e] = (_Float16)0.f; Al[e] = (_Float16)0.f; }
    for (int e = tid; e < 4 * RPB * 8; e += NTHR)   { xh[e] = (_Float16)0.f; xl[e] = (_Float16)0.f; }
    {
        const uint4* src = (const uint4*)Wio_g;
        uint4* dst = (uint4*)Wio;
        for (int e = tid; e < (4 * WIN_E) / 8; e += NTHR) dst[e] = src[e];
    }
    __syncthreads();
    // Stage x for t=0
    for (int e = tid; e < RPB * 28; e += NTHR) {
        int m = e / 28, f = e % 28;
        float v = x[((size_t)(row0 + m) * 64 + 0) * 28 + f];
        _Float16 h = (_Float16)v;
        int ix = ((f >> 3) * RPB + m) * 8 + (f & 7);
        xh[ix] = h; xl[ix] = (_Float16)(v - (float)h);
    }

    const int Ttot = 64 + *rsteps_p;

    const f16x8* Bph = (const f16x8*)Bh_g;
    const f16x8* Bpl = (const f16x8*)Bl_g;
    const f16x8* Aph = (const f16x8*)Ah;
    const f16x8* Apl = (const f16x8*)Al;
    const f16x8* Xph = (const f16x8*)xh;
    const f16x8* Xpl = (const f16x8*)xl;
    const f16x8* Wp  = (const f16x8*)Wio;
    const int bb = quad * NPAD + w * (NTILE * 16) + l15;  // B-frag base (f16x8 units)
    const int ab = quad * RPB + l15;                      // A-frag base (f16x8 units)

    // ---- Pin step-invariant B_hi fragments in registers: 3 x 12 x 4 = 144 VGPRs ----
    f16x8 bhr[12][NTILE];
#pragma unroll
    for (int kt = 0; kt < 12; ++kt)
#pragma unroll
        for (int i = 0; i < NTILE; ++i)
            bhr[kt][i] = Bph[bb + i * 16 + kt * (4 * NPAD)];

    for (int t = 0; t < Ttot; ++t) {
        __syncthreads();   // barrier A: spikes/x for step t visible

        f32x4 acc[NTILE];
#pragma unroll
        for (int i = 0; i < NTILE; ++i) acc[i] = (f32x4){0.f, 0.f, 0.f, 0.f};

        // ---- Recurrent GEMM: acc[m][n] += sum_k spk[m][k] * W_rec[n][k] ----
        // B_hi from registers; B_lo streamed from L2. Fully unrolled (register
        // indexing of bhr is mandatory — dynamic index would spill to scratch).
#pragma unroll
        for (int kt = 0; kt < 12; ++kt) {
            f16x8 ah = Aph[ab + kt * 64];
            f16x8 al = Apl[ab + kt * 64];
#pragma unroll
            for (int i = 0; i < NTILE; ++i) {
                f16x8 bl = Bpl[bb + i * 16 + kt * (4 * NPAD)];
                acc[i] = __builtin_amdgcn_mfma_f32_16x16x32_f16(ah, bhr[kt][i], acc[i], 0, 0, 0);
                acc[i] = __builtin_amdgcn_mfma_f32_16x16x32_f16(al, bhr[kt][i], acc[i], 0, 0, 0);
                acc[i] = __builtin_amdgcn_mfma_f32_16x16x32_f16(ah, bl,         acc[i], 0, 0, 0);
            }
        }

        // ---- Gated input via MFMA from LDS weights (scan phase) ----
        if (t < 64) {
            f16x8 xa = Xph[ab];
            f16x8 xb = Xpl[ab];
#pragma unroll
            for (int i = 0; i < NTILE; ++i) {
                f16x8 ih = Wp[0 * (WIN_E / 8) + bb + i * 16];
                f16x8 il = Wp[1 * (WIN_E / 8) + bb + i * 16];
                f16x8 gh = Wp[2 * (WIN_E / 8) + bb + i * 16];
                f16x8 gl = Wp[3 * (WIN_E / 8) + bb + i * 16];
                f32x4 ia = (f32x4){binv[i], binv[i], binv[i], binv[i]};
                f32x4 ga = (f32x4){bgtv[i], bgtv[i], bgtv[i], bgtv[i]};
                ia = __builtin_amdgcn_mfma_f32_16x16x32_f16(xa, ih, ia, 0, 0, 0);
                ia = __builtin_amdgcn_mfma_f32_16x16x32_f16(xb, ih, ia, 0, 0, 0);
                ia = __builtin_amdgcn_mfma_f32_16x16x32_f16(xa, il, ia, 0, 0, 0);
                ga = __builtin_amdgcn_mfma_f32_16x16x32_f16(xa, gh, ga, 0, 0, 0);
                ga = __builtin_amdgcn_mfma_f32_16x16x32_f16(xb, gh, ga, 0, 0, 0);
                ga = __builtin_amdgcn_mfma_f32_16x16x32_f16(xa, gl, ga, 0, 0, 0);
#pragma unroll
                for (int r = 0; r < 4; ++r) acc[i][r] += ia[r] * sigm(ga[r]);
            }
        }

        // ---- LayerNorm stats: reduce over n (16 l15-lanes, then 8 waves) ----
#pragma unroll
        for (int r = 0; r < 4; ++r) {
            float v = 0.f, v2 = 0.f;
#pragma unroll
            for (int i = 0; i < NTILE; ++i) { v += acc[i][r]; v2 += acc[i][r] * acc[i][r]; }
#pragma unroll
            for (int off = 1; off < 16; off <<= 1) {
                v  += __shfl_xor(v,  off);
                v2 += __shfl_xor(v2, off);
            }
            if (l15 == 0) { red[w][quad * 4 + r][0] = v; red[w][quad * 4 + r][1] = v2; }
        }
        __syncthreads();   // barrier B
        if (tid < RPB) {
            float s = 0.f, s2 = 0.f;
#pragma unroll
            for (int w2 = 0; w2 < 8; ++w2) { s += red[w2][tid][0]; s2 += red[w2][tid][1]; }
            float mu  = s * (1.f / NET);
            float var = s2 * (1.f / NET) - mu * mu;
            musig[0][tid] = mu;
            musig[1][tid] = rsqrtf(var + 1e-5f);
        }
        __syncthreads();   // barrier C

        float mu_r[4], rs_r[4];
#pragma unroll
        for (int r = 0; r < 4; ++r) { mu_r[r] = musig[0][quad * 4 + r]; rs_r[r] = musig[1][quad * 4 + r]; }

        // ---- LN apply + PulseTGAU neuron, write split spikes to A-layout ----
#pragma unroll
        for (int i = 0; i < NTILE; ++i) {
            int n_i  = (w * NTILE + i) * 16 + l15;
            int base = ((n_i >> 3) * RPB) * 8 + (n_i & 7);
#pragma unroll
            for (int r = 0; r < 4; ++r) {
                int m = quad * 4 + r;
                float cur = (acc[i][r] - mu_r[r]) * rs_r[r] * gam[i] + bet[i];
                float p   = pot[i][r] * 0.95f + cur + intv[i];
                float gp  = p - thrv[i];
                float sg  = sigm(gp * asp[i]);
                float sp  = sigm(gp);
                float o   = gp * sp * sg;
                pot[i][r] = p - rscv[i] * (gp * sg);
                _Float16 h = (_Float16)o;
                Ah[base + m * 8] = h;
                Al[base + m * 8] = (_Float16)(o - (float)h);
            }
        }

        // Stage x for t+1 (xh reads for step t all happened before barrier B)
        if (t < 63) {
            for (int e = tid; e < RPB * 28; e += NTHR) {
                int m = e / 28, f = e % 28;
                float v = x[((size_t)(row0 + m) * 64 + (t + 1)) * 28 + f];
                _Float16 h = (_Float16)v;
                int ix = ((f >> 3) * RPB + m) * 8 + (f & 7);
                xh[ix] = h; xl[ix] = (_Float16)(v - (float)h);
            }
        }
    }

    __syncthreads();
    // ---- Classifier epilogue ----
    if (tid < RPB * 10) {
        int r = tid / 10, c = tid - r * 10;
        const float* wc = W_cls + c * NET;
        float s = b_cls[c];
        for (int k = 0; k < NET; ++k) {
            int ix = ((k >> 3) * RPB + r) * 8 + (k & 7);
            float sv = (float)Ah[ix] + (float)Al[ix];
            s = fmaf(sv, wc[k], s);
        }
        out[(size_t)(row0 + r) * 10 + c] = s;
    }
}

extern "C" void kernel_launch(void* const* d_in, const int* in_sizes, int n_in,
                              void* d_out, int out_size, void* d_ws, size_t ws_size,
                              hipStream_t stream)
{
    const float* x      = (const float*)d_in[0];
    const int*   rsteps = (const int*)  d_in[1];
    const float* W_in   = (const float*)d_in[2];
    const float* b_in   = (const float*)d_in[3];
    const float* W_gate = (const float*)d_in[4];
    const float* b_gate = (const float*)d_in[5];
    const float* W_rec  = (const float*)d_in[6];
    const float* ln_g   = (const float*)d_in[7];
    const float* ln_b   = (const float*)d_in[8];
    const float* thr    = (const float*)d_in[9];
    const float* intr   = (const float*)d_in[10];
    const float* steep  = (const float*)d_in[11];
    const float* rsc    = (const float*)d_in[12];
    const float* W_cls  = (const float*)d_in[13];
    const float* b_cls  = (const float*)d_in[14];
    float*       out    = (float*)d_out;

    _Float16* Bh  = (_Float16*)d_ws;
    _Float16* Bl  = Bh + WREC_E;
    _Float16* Wio = Bl + WREC_E;     // 4*WIN_E: Wih, Wil, Wgh, Wgl

    const int total = WREC_E + 2 * WIN_E;
    prep_kernel<<<dim3((total + 255) / 256), dim3(256), 0, stream>>>(
        W_rec, W_in, W_gate, Bh, Bl, Wio);
    resonator_kernel<<<dim3(NBLK), dim3(NTHR), 0, stream>>>(
        x, rsteps, b_in, b_gate, ln_g, ln_b, thr, intr, steep, rsc,
        W_cls, b_cls, Bh, Bl, Wio, out);
}